// Round 17
// baseline (384.647 us; speedup 1.0000x reference)
//
#include <hip/hip_runtime.h>
#include <hip/hip_bf16.h>

// 2-layer GCN on MI355X.
// out[v] = dinv[v] * ( sum_{e: dst=v} g[src_e] + g[v] ) + b,  g = (x@W) * dinv[row]
// CSR build = bucketed counting sort, ALL atomics in LDS.
// r17: G stored COLUMN-SLICED  Gs[slice=col/8][node][8 bf16]; aggregate grid
// uses slice = blockIdx.x & 7 so (round-robin dispatch heuristic) each XCD
// gathers from a 1.6 MB L2-resident slice. r5-r16 evidence: FETCH pinned at
// ~88 MB = 8 XCDs x 12.8 MB compulsory duplication; slicing attacks that.
// agg1 writes bf16 sliced x2 (gemm2 rounds to bf16 anyway -> identical
// numerics); sliced layout == MFMA A-fragment order -> gemm2 A = one 16B load.

#define FDIM 64    // HID_DIM == OUT_DIM
#define NPB  128   // nodes per bucket (dst >> 7)
#define MAXB1 800  // >= ceil(100000/128)=782

typedef __attribute__((ext_vector_type(8))) short bf16x8;   // MFMA A/B frag
typedef __attribute__((ext_vector_type(4))) float f32x4;    // MFMA C/D frag

// bf16 helpers (bit-level RTN; finite data only)
static __device__ __forceinline__ unsigned short f2bf(float f) {
    unsigned int u = __float_as_uint(f);
    unsigned int r = 0x7FFFu + ((u >> 16) & 1u);
    return (unsigned short)((u + r) >> 16);
}
static __device__ __forceinline__ float lof(unsigned int u) {
    return __uint_as_float(u << 16);
}
static __device__ __forceinline__ float hif(unsigned int u) {
    return __uint_as_float(u & 0xFFFF0000u);
}

// ---------------- phase 1a: per-block bucket histogram ----------------
__global__ __launch_bounds__(256) void bucket_hist(const int* __restrict__ dst, int E,
                                                   int B1, int chunk, int B0,
                                                   int* __restrict__ H) {
    __shared__ int hist[MAXB1];
    const int blk = blockIdx.x, t = threadIdx.x;
    for (int i = t; i < B1; i += 256) hist[i] = 0;
    __syncthreads();
    const int beg = blk * chunk, end = min(E, beg + chunk);
    for (int e = beg + t; e < end; e += 256) atomicAdd(&hist[dst[e] >> 7], 1);
    __syncthreads();
    for (int i = t; i < B1; i += 256) H[i * B0 + blk] = hist[i];  // bin-major
}

// ---------------- scan A: per-block sums over spans of 2048 ----------------
__global__ __launch_bounds__(256) void scanA(const int* __restrict__ a, int S,
                                             int* __restrict__ bs) {
    __shared__ int s[256];
    const int blk = blockIdx.x, t = threadIdx.x;
    const int base = blk * 2048 + t * 8;
    int sum = 0;
    #pragma unroll
    for (int j = 0; j < 8; ++j) { int idx = base + j; if (idx < S) sum += a[idx]; }
    s[t] = sum;
    __syncthreads();
    for (int off = 128; off > 0; off >>= 1) {
        if (t < off) s[t] += s[t + off];
        __syncthreads();
    }
    if (t == 0) bs[blk] = s[0];
}

// ---------------- scan B: exclusive scan of block sums (nB <= 512) ----------
__global__ __launch_bounds__(512) void scanB(int* __restrict__ bs, int nB) {
    __shared__ int s[512];
    const int t = threadIdx.x;
    int v = (t < nB) ? bs[t] : 0;
    s[t] = v;
    __syncthreads();
    for (int off = 1; off < 512; off <<= 1) {
        int x = s[t];
        int y = (t >= off) ? s[t - off] : 0;
        __syncthreads();
        s[t] = x + y;
        __syncthreads();
    }
    if (t < nB) bs[t] = s[t] - v;
}

// ---------------- scan C: in-place exclusive scan (span 2048/block) ---------
__global__ __launch_bounds__(256) void scanC(int* __restrict__ a, int S,
                                             const int* __restrict__ bs) {
    __shared__ int s[256];
    const int blk = blockIdx.x, t = threadIdx.x;
    const int base = blk * 2048 + t * 8;
    int v[8];
    int sum = 0;
    #pragma unroll
    for (int j = 0; j < 8; ++j) { int idx = base + j; v[j] = (idx < S) ? a[idx] : 0; sum += v[j]; }
    s[t] = sum;
    __syncthreads();
    const int own = sum;
    for (int off = 1; off < 256; off <<= 1) {
        int x = s[t];
        int y = (t >= off) ? s[t - off] : 0;
        __syncthreads();
        s[t] = x + y;
        __syncthreads();
    }
    int run = bs[blk] + s[t] - own;
    #pragma unroll
    for (int j = 0; j < 8; ++j) { int idx = base + j; if (idx < S) a[idx] = run; run += v[j]; }
}

// ------- phase 1b: scatter edges into bucket-grouped packed (dlow7,src) -----
__global__ __launch_bounds__(256) void bucket_scatter(const int* __restrict__ src,
                                                      const int* __restrict__ dst,
                                                      int E, int B1, int chunk, int B0,
                                                      const int* __restrict__ Hs,
                                                      int* __restrict__ pairs) {
    __shared__ int cur[MAXB1];
    const int blk = blockIdx.x, t = threadIdx.x;
    for (int i = t; i < B1; i += 256) cur[i] = Hs[i * B0 + blk];
    __syncthreads();
    const int beg = blk * chunk, end = min(E, beg + chunk);
    for (int e = beg + t; e < end; e += 256) {
        int d = dst[e];
        int pos = atomicAdd(&cur[d >> 7], 1);          // LDS atomic
        pairs[pos] = ((d & 127) << 17) | src[e];       // src < 2^17
    }
}

// ---------------- phase 2: per-bucket local counting sort -> CSR ------------
__global__ __launch_bounds__(256) void bucket_csr(const int* __restrict__ pairs,
                                                  const int* __restrict__ Hs,
                                                  int B0, int E, int N,
                                                  float* __restrict__ dinv,
                                                  int* __restrict__ rowStart,
                                                  int* __restrict__ srcSorted) {
    __shared__ int hist[NPB], pref[NPB], cur[NPB];
    const int b = blockIdx.x, t = threadIdx.x;
    const int B1 = gridDim.x;
    const int vbase = b * NPB;
    const int nv = min(NPB, N - vbase);
    const int estart = Hs[b * B0];
    const int eend = (b + 1 < B1) ? Hs[(b + 1) * B0] : E;

    if (t < NPB) hist[t] = 0;
    __syncthreads();
    for (int e = estart + t; e < eend; e += 256)
        atomicAdd(&hist[pairs[e] >> 17], 1);
    __syncthreads();

    if (t < NPB) pref[t] = hist[t];
    __syncthreads();
    for (int off = 1; off < NPB; off <<= 1) {
        int v = 0;
        if (t < NPB && t >= off) v = pref[t - off];
        __syncthreads();
        if (t < NPB) pref[t] += v;
        __syncthreads();
    }
    if (t < nv) {
        int ex = pref[t] - hist[t];
        rowStart[vbase + t] = estart + ex;
        dinv[vbase + t] = rsqrtf((float)(hist[t] + 1));
        cur[t] = estart + ex;
    }
    if (b == B1 - 1 && t == 0) rowStart[N] = E;
    __syncthreads();
    for (int e = estart + t; e < eend; e += 256) {
        int p = pairs[e];
        int pos = atomicAdd(&cur[p >> 17], 1);       // LDS atomic
        srcSorted[pos] = p & 0x1FFFF;
    }
}

// ------- GEMM via MFMA 16x16x32 bf16, SLICED output ------------------------
// One 16-row slab per wave, W register-resident, no LDS/barriers.
// Output: Gs ushort index ((col>>3)*N + row)*8 + (col&7)   [slice-major].
// ABF16=1: A read directly from sliced bf16 (slice 4s+lg = one 16B load).
template <int K, int ABF16>
__global__ __launch_bounds__(256, 2) void gemm_mfma(const float* __restrict__ X,
                                                    const float* __restrict__ W,
                                                    const float* __restrict__ dinv,
                                                    unsigned short* __restrict__ G, int N) {
    const int lane = threadIdx.x & 63;
    const int lr   = lane & 15;        // A-row / B-col / D-col within tile
    const int lg   = lane >> 4;        // k-group and D-row group
    const int wid  = (blockIdx.x * blockDim.x + threadIdx.x) >> 6;
    const int nW   = (gridDim.x * blockDim.x) >> 6;
    constexpr int NS = K / 32;

    // ---- W -> register B-fragments (L2-resident; once per wave) ----
    bf16x8 bf[NS][4];
    #pragma unroll
    for (int s = 0; s < NS; ++s) {
        #pragma unroll
        for (int c = 0; c < 4; ++c) {
            const float* wp = W + (size_t)(s * 32 + lg * 8) * FDIM + c * 16 + lr;
            bf16x8 v;
            #pragma unroll
            for (int j = 0; j < 8; ++j) v[j] = (short)f2bf(wp[(size_t)j * FDIM]);
            bf[s][c] = v;
        }
    }

    const int nSlab = N >> 4;          // N = 100000 -> 6250 slabs, no tail
    for (int sl = wid; sl < nSlab; sl += nW) {
        const int row0 = sl << 4;

        bf16x8 af[NS];
        if (ABF16) {
            // sliced bf16 input: lane's 8 k-values = slice (4s+lg), node row0+lr
            const unsigned short* Xb = reinterpret_cast<const unsigned short*>(X);
            #pragma unroll
            for (int s = 0; s < NS; ++s)
                af[s] = *reinterpret_cast<const bf16x8*>(
                    Xb + ((size_t)(4 * s + lg) * N + row0 + lr) * 8);
        } else {
            const float* xp = X + (size_t)(row0 + lr) * K + lg * 8;
            #pragma unroll
            for (int s = 0; s < NS; ++s) {
                float4 x0 = *reinterpret_cast<const float4*>(xp + s * 32);
                float4 x1 = *reinterpret_cast<const float4*>(xp + s * 32 + 4);
                bf16x8 v;
                v[0] = (short)f2bf(x0.x); v[1] = (short)f2bf(x0.y);
                v[2] = (short)f2bf(x0.z); v[3] = (short)f2bf(x0.w);
                v[4] = (short)f2bf(x1.x); v[5] = (short)f2bf(x1.y);
                v[6] = (short)f2bf(x1.z); v[7] = (short)f2bf(x1.w);
                af[s] = v;
            }
        }

        f32x4 acc[4];
        #pragma unroll
        for (int c = 0; c < 4; ++c) acc[c] = (f32x4){0.f, 0.f, 0.f, 0.f};

        #pragma unroll
        for (int s = 0; s < NS; ++s) {
            #pragma unroll
            for (int c = 0; c < 4; ++c)
                acc[c] = __builtin_amdgcn_mfma_f32_16x16x32_bf16(af[s], bf[s][c], acc[c], 0, 0, 0);
        }

        // epilogue: lane l, reg i, tile c -> row=row0+4*lg+i, col=16c+lr
        // sliced store: slice = 2c + (lr>>3), within = lr&7
        const int rb = row0 + lg * 4;
        const float dv0 = dinv[rb + 0];
        const float dv1 = dinv[rb + 1];
        const float dv2 = dinv[rb + 2];
        const float dv3 = dinv[rb + 3];
        #pragma unroll
        for (int c = 0; c < 4; ++c) {
            unsigned short* gp = G + ((size_t)(2 * c + (lr >> 3)) * N + rb) * 8 + (lr & 7);
            gp[0 * 8] = f2bf(acc[c][0] * dv0);
            gp[1 * 8] = f2bf(acc[c][1] * dv1);
            gp[2 * 8] = f2bf(acc[c][2] * dv2);
            gp[3 * 8] = f2bf(acc[c][3] * dv3);
        }
    }
}

// ------- aggregate, XCD-sliced: slice = blockIdx & 7 -------------------------
// Lane: q=lane>>2 (edge slot, 16 edges/round), j=lane&3 (uint within slice).
// Gather working set per XCD = one 1.6 MB slice (L2-resident). Node reduce =
// shfl_xor strides 4/8/16/32. OUTBF16: write sliced bf16 (+ReLU); else fp32
// row-major final output.
template <int OUTBF16>
__global__ __launch_bounds__(256, 4) void aggregate_sl(const unsigned int* __restrict__ Gs,
                                                       const int* __restrict__ rowStart,
                                                       const int* __restrict__ srcSorted,
                                                       const float* __restrict__ dinv,
                                                       const float* __restrict__ bias,
                                                       void* __restrict__ OUT, int N) {
    const int lane = threadIdx.x & 63;
    const int q    = lane >> 2;          // edge slot 0..15
    const int j    = lane & 3;           // uint within 8-feature slice
    const int s    = blockIdx.x & 7;     // slice == XCD (dispatch heuristic)
    const int wid  = (blockIdx.x >> 3) * (blockDim.x >> 6) + (threadIdx.x >> 6);
    const int nW   = (gridDim.x >> 3) * (blockDim.x >> 6);
    const float bx = bias[s * 8 + 2 * j];
    const float by = bias[s * 8 + 2 * j + 1];
    const unsigned int* Gss = Gs + (size_t)s * N * 4;

    for (int v = wid; v < N; v += nW) {
        const int beg = rowStart[v];
        const int end = rowStart[v + 1];

        unsigned int us = Gss[(size_t)v * 4 + j];     // self (q==0 counts it)
        float ax = (q == 0) ? lof(us) : 0.f;
        float ay = (q == 0) ? hif(us) : 0.f;

        int e = beg;
        for (; e + 16 <= end; e += 16) {              // full 16-edge rounds
            int ii = srcSorted[e + q];
            unsigned int u = Gss[(size_t)ii * 4 + j];
            ax += lof(u); ay += hif(u);
        }
        if (e < end) {                                // masked final round
            int ii = srcSorted[min(e + q, end - 1)];
            unsigned int u = Gss[(size_t)ii * 4 + j];
            if (e + q < end) { ax += lof(u); ay += hif(u); }
        }

        // reduce over the 16 edge slots (bits 2..5 of lane)
        ax += __shfl_xor(ax, 4, 64);   ay += __shfl_xor(ay, 4, 64);
        ax += __shfl_xor(ax, 8, 64);   ay += __shfl_xor(ay, 8, 64);
        ax += __shfl_xor(ax, 16, 64);  ay += __shfl_xor(ay, 16, 64);
        ax += __shfl_xor(ax, 32, 64);  ay += __shfl_xor(ay, 32, 64);

        if (q == 0) {
            const float dv = dinv[v];
            float rx = ax * dv + bx;
            float ry = ay * dv + by;
            if (OUTBF16) {                            // layer 1: ReLU + bf16 sliced
                rx = fmaxf(rx, 0.f); ry = fmaxf(ry, 0.f);
                unsigned int p = (unsigned)f2bf(rx) | ((unsigned)f2bf(ry) << 16);
                ((unsigned int*)OUT)[((size_t)s * N + v) * 4 + j] = p;
            } else {                                  // layer 2: fp32 row-major
                float2 r2; r2.x = rx; r2.y = ry;
                *reinterpret_cast<float2*>((float*)OUT + (size_t)v * FDIM + s * 8 + 2 * j) = r2;
            }
        }
    }
}

extern "C" void kernel_launch(void* const* d_in, const int* in_sizes, int n_in,
                              void* d_out, int out_size, void* d_ws, size_t ws_size,
                              hipStream_t stream) {
    const float* x     = (const float*)d_in[0];
    const int*   edges = (const int*)d_in[1];   // int32 per harness contract
    const float* W1    = (const float*)d_in[2];
    const float* b1    = (const float*)d_in[3];
    const float* W2    = (const float*)d_in[4];
    const float* b2    = (const float*)d_in[5];
    float*       out   = (float*)d_out;

    const int N = in_sizes[0] / 128;   // 100000
    const int E = in_sizes[1] / 2;     // 1600000
    const int* srcIdx = edges;
    const int* dstIdx = edges + E;

    const int B1 = (N + NPB - 1) / NPB;         // 782 buckets
    const int B0 = 256;                          // phase-1 blocks
    const int chunk = (E + B0 - 1) / B0;         // 6250
    const int S  = B1 * B0;                      // scanned size (200192)
    const int nSB = (S + 2047) / 2048;           // 98 scan blocks (<=512)

    // workspace layout (256B aligned slices)
    char* ws = (char*)d_ws;
    size_t off = 0;
    auto alloc = [&](size_t bytes) { char* p = ws + off; off = (off + bytes + 255) & ~(size_t)255; return p; };
    float* dinv      = (float*)alloc((size_t)N * 4);
    int*   H         = (int*)  alloc((size_t)S * 4);
    int*   blockSums = (int*)  alloc(512 * 4);
    int*   rowStart  = (int*)  alloc((size_t)(N + 1) * 4);
    int*   srcSorted = (int*)  alloc((size_t)E * 4);
    unsigned short* g1  = (unsigned short*)alloc((size_t)N * FDIM * 2);  // bf16 sliced
    unsigned short* x2b = (unsigned short*)alloc((size_t)N * FDIM * 2);  // bf16 sliced
    int*   pairs     = (int*)x2b;       // alias: pairs (6.4MB) dead before x2b written
    unsigned short* g2 = g1;            // g1 dead after first aggregate

    bucket_hist   <<<B0, 256, 0, stream>>>(dstIdx, E, B1, chunk, B0, H);
    scanA         <<<nSB, 256, 0, stream>>>(H, S, blockSums);
    scanB         <<<1, 512, 0, stream>>>(blockSums, nSB);
    scanC         <<<nSB, 256, 0, stream>>>(H, S, blockSums);
    bucket_scatter<<<B0, 256, 0, stream>>>(srcIdx, dstIdx, E, B1, chunk, B0, H, pairs);
    bucket_csr    <<<B1, 256, 0, stream>>>(pairs, H, B0, E, N, dinv, rowStart, srcSorted);

    gemm_mfma<128, 0><<<768, 256, 0, stream>>>(x, W1, dinv, g1, N);
    aggregate_sl<1>  <<<8192, 256, 0, stream>>>((const unsigned int*)g1, rowStart, srcSorted,
                                                dinv, b1, (void*)x2b, N);
    gemm_mfma<64, 1> <<<768, 256, 0, stream>>>((const float*)x2b, W2, dinv, g2, N);
    aggregate_sl<0>  <<<8192, 256, 0, stream>>>((const unsigned int*)g2, rowStart, srcSorted,
                                                dinv, b2, (void*)out, N);
}

// Round 18
// 162.651 us; speedup vs baseline: 2.3649x; 2.3649x over previous
//
#include <hip/hip_runtime.h>
#include <hip/hip_bf16.h>

// 2-layer GCN on MI355X.
// out[v] = dinv[v] * ( sum_{e: dst=v} g[src_e] + g[v] ) + b,  g = (x@W) * dinv[row]
// CSR build = bucketed counting sort, ALL atomics in LDS.
// r18 = r16 (best, 163 us) + bf16 intermediate h (agg1 writes ReLU'd bf16;
// gemm2 reads bf16 A-fragments directly). r17 lesson: XCD slicing cut FETCH
// 88->34 MB but 8x'd per-node latency chains (42->160 us) — reverted.

#define FDIM 64    // HID_DIM == OUT_DIM
#define NPB  128   // nodes per bucket (dst >> 7)
#define MAXB1 800  // >= ceil(100000/128)=782

typedef __attribute__((ext_vector_type(8))) short bf16x8;   // MFMA A/B frag
typedef __attribute__((ext_vector_type(4))) float f32x4;    // MFMA C/D frag

// bf16 helpers (bit-level RTN; finite data only)
static __device__ __forceinline__ unsigned short f2bf(float f) {
    unsigned int u = __float_as_uint(f);
    unsigned int r = 0x7FFFu + ((u >> 16) & 1u);
    return (unsigned short)((u + r) >> 16);
}
static __device__ __forceinline__ float lof(unsigned int u) {
    return __uint_as_float(u << 16);
}
static __device__ __forceinline__ float hif(unsigned int u) {
    return __uint_as_float(u & 0xFFFF0000u);
}

// ---------------- phase 1a: per-block bucket histogram ----------------
__global__ __launch_bounds__(256) void bucket_hist(const int* __restrict__ dst, int E,
                                                   int B1, int chunk, int B0,
                                                   int* __restrict__ H) {
    __shared__ int hist[MAXB1];
    const int blk = blockIdx.x, t = threadIdx.x;
    for (int i = t; i < B1; i += 256) hist[i] = 0;
    __syncthreads();
    const int beg = blk * chunk, end = min(E, beg + chunk);
    for (int e = beg + t; e < end; e += 256) atomicAdd(&hist[dst[e] >> 7], 1);
    __syncthreads();
    for (int i = t; i < B1; i += 256) H[i * B0 + blk] = hist[i];  // bin-major
}

// ---------------- scan A: per-block sums over spans of 2048 ----------------
__global__ __launch_bounds__(256) void scanA(const int* __restrict__ a, int S,
                                             int* __restrict__ bs) {
    __shared__ int s[256];
    const int blk = blockIdx.x, t = threadIdx.x;
    const int base = blk * 2048 + t * 8;
    int sum = 0;
    #pragma unroll
    for (int j = 0; j < 8; ++j) { int idx = base + j; if (idx < S) sum += a[idx]; }
    s[t] = sum;
    __syncthreads();
    for (int off = 128; off > 0; off >>= 1) {
        if (t < off) s[t] += s[t + off];
        __syncthreads();
    }
    if (t == 0) bs[blk] = s[0];
}

// ---------------- scan B: exclusive scan of block sums (nB <= 512) ----------
__global__ __launch_bounds__(512) void scanB(int* __restrict__ bs, int nB) {
    __shared__ int s[512];
    const int t = threadIdx.x;
    int v = (t < nB) ? bs[t] : 0;
    s[t] = v;
    __syncthreads();
    for (int off = 1; off < 512; off <<= 1) {
        int x = s[t];
        int y = (t >= off) ? s[t - off] : 0;
        __syncthreads();
        s[t] = x + y;
        __syncthreads();
    }
    if (t < nB) bs[t] = s[t] - v;
}

// ---------------- scan C: in-place exclusive scan (span 2048/block) ---------
__global__ __launch_bounds__(256) void scanC(int* __restrict__ a, int S,
                                             const int* __restrict__ bs) {
    __shared__ int s[256];
    const int blk = blockIdx.x, t = threadIdx.x;
    const int base = blk * 2048 + t * 8;
    int v[8];
    int sum = 0;
    #pragma unroll
    for (int j = 0; j < 8; ++j) { int idx = base + j; v[j] = (idx < S) ? a[idx] : 0; sum += v[j]; }
    s[t] = sum;
    __syncthreads();
    const int own = sum;
    for (int off = 1; off < 256; off <<= 1) {
        int x = s[t];
        int y = (t >= off) ? s[t - off] : 0;
        __syncthreads();
        s[t] = x + y;
        __syncthreads();
    }
    int run = bs[blk] + s[t] - own;
    #pragma unroll
    for (int j = 0; j < 8; ++j) { int idx = base + j; if (idx < S) a[idx] = run; run += v[j]; }
}

// ------- phase 1b: scatter edges into bucket-grouped packed (dlow7,src) -----
__global__ __launch_bounds__(256) void bucket_scatter(const int* __restrict__ src,
                                                      const int* __restrict__ dst,
                                                      int E, int B1, int chunk, int B0,
                                                      const int* __restrict__ Hs,
                                                      int* __restrict__ pairs) {
    __shared__ int cur[MAXB1];
    const int blk = blockIdx.x, t = threadIdx.x;
    for (int i = t; i < B1; i += 256) cur[i] = Hs[i * B0 + blk];
    __syncthreads();
    const int beg = blk * chunk, end = min(E, beg + chunk);
    for (int e = beg + t; e < end; e += 256) {
        int d = dst[e];
        int pos = atomicAdd(&cur[d >> 7], 1);          // LDS atomic
        pairs[pos] = ((d & 127) << 17) | src[e];       // src < 2^17
    }
}

// ---------------- phase 2: per-bucket local counting sort -> CSR ------------
__global__ __launch_bounds__(256) void bucket_csr(const int* __restrict__ pairs,
                                                  const int* __restrict__ Hs,
                                                  int B0, int E, int N,
                                                  float* __restrict__ dinv,
                                                  int* __restrict__ rowStart,
                                                  int* __restrict__ srcSorted) {
    __shared__ int hist[NPB], pref[NPB], cur[NPB];
    const int b = blockIdx.x, t = threadIdx.x;
    const int B1 = gridDim.x;
    const int vbase = b * NPB;
    const int nv = min(NPB, N - vbase);
    const int estart = Hs[b * B0];
    const int eend = (b + 1 < B1) ? Hs[(b + 1) * B0] : E;

    if (t < NPB) hist[t] = 0;
    __syncthreads();
    for (int e = estart + t; e < eend; e += 256)
        atomicAdd(&hist[pairs[e] >> 17], 1);
    __syncthreads();

    if (t < NPB) pref[t] = hist[t];
    __syncthreads();
    for (int off = 1; off < NPB; off <<= 1) {
        int v = 0;
        if (t < NPB && t >= off) v = pref[t - off];
        __syncthreads();
        if (t < NPB) pref[t] += v;
        __syncthreads();
    }
    if (t < nv) {
        int ex = pref[t] - hist[t];
        rowStart[vbase + t] = estart + ex;
        dinv[vbase + t] = rsqrtf((float)(hist[t] + 1));
        cur[t] = estart + ex;
    }
    if (b == B1 - 1 && t == 0) rowStart[N] = E;
    __syncthreads();
    for (int e = estart + t; e < eend; e += 256) {
        int p = pairs[e];
        int pos = atomicAdd(&cur[p >> 17], 1);       // LDS atomic
        srcSorted[pos] = p & 0x1FFFF;
    }
}

// ------- GEMM via MFMA 16x16x32 bf16: one 16-row slab per wave --------------
// W register-resident (16 B-fragments), no LDS, no barriers. N=100000=6250
// slabs, no tail. ABF16=1: A rows are packed bf16 (one 16B load per frag).
// Layouts (HW-verified m89): A lane l -> row l&15, k=32s+8*(l>>4)+j ;
// B lane l -> col l&15 ; C/D lane l reg i -> col l&15, row 4*(l>>4)+i.
template <int K, int ABF16>
__global__ __launch_bounds__(256, 2) void gemm_mfma(const float* __restrict__ X,
                                                    const float* __restrict__ W,
                                                    const float* __restrict__ dinv,
                                                    unsigned short* __restrict__ G, int N) {
    const int lane = threadIdx.x & 63;
    const int lr   = lane & 15;        // A-row / B-col / D-col within tile
    const int lg   = lane >> 4;        // k-group and D-row group
    const int wid  = (blockIdx.x * blockDim.x + threadIdx.x) >> 6;
    const int nW   = (gridDim.x * blockDim.x) >> 6;
    constexpr int NS = K / 32;

    // ---- W -> register B-fragments (L2-resident; once per wave) ----
    bf16x8 bf[NS][4];
    #pragma unroll
    for (int s = 0; s < NS; ++s) {
        #pragma unroll
        for (int c = 0; c < 4; ++c) {
            const float* wp = W + (size_t)(s * 32 + lg * 8) * FDIM + c * 16 + lr;
            bf16x8 v;
            #pragma unroll
            for (int j = 0; j < 8; ++j) v[j] = (short)f2bf(wp[(size_t)j * FDIM]);
            bf[s][c] = v;
        }
    }

    const int nSlab = N >> 4;          // N = 100000 -> 6250 slabs, no tail
    for (int sl = wid; sl < nSlab; sl += nW) {
        const int row0 = sl << 4;

        bf16x8 af[NS];
        if (ABF16) {
            // packed bf16 rows: lane's 8 k-values = one aligned 16B load
            const unsigned short* xp =
                reinterpret_cast<const unsigned short*>(X) + (size_t)(row0 + lr) * K + lg * 8;
            #pragma unroll
            for (int s = 0; s < NS; ++s)
                af[s] = *reinterpret_cast<const bf16x8*>(xp + s * 32);
        } else {
            const float* xp = X + (size_t)(row0 + lr) * K + lg * 8;
            #pragma unroll
            for (int s = 0; s < NS; ++s) {
                float4 x0 = *reinterpret_cast<const float4*>(xp + s * 32);
                float4 x1 = *reinterpret_cast<const float4*>(xp + s * 32 + 4);
                bf16x8 v;
                v[0] = (short)f2bf(x0.x); v[1] = (short)f2bf(x0.y);
                v[2] = (short)f2bf(x0.z); v[3] = (short)f2bf(x0.w);
                v[4] = (short)f2bf(x1.x); v[5] = (short)f2bf(x1.y);
                v[6] = (short)f2bf(x1.z); v[7] = (short)f2bf(x1.w);
                af[s] = v;
            }
        }

        f32x4 acc[4];
        #pragma unroll
        for (int c = 0; c < 4; ++c) acc[c] = (f32x4){0.f, 0.f, 0.f, 0.f};

        #pragma unroll
        for (int s = 0; s < NS; ++s) {
            #pragma unroll
            for (int c = 0; c < 4; ++c)
                acc[c] = __builtin_amdgcn_mfma_f32_16x16x32_bf16(af[s], bf[s][c], acc[c], 0, 0, 0);
        }

        // epilogue: lane l, reg i, tile c -> row=row0+4*lg+i, col=16c+lr
        const int rb = row0 + lg * 4;
        const float dv0 = dinv[rb + 0];
        const float dv1 = dinv[rb + 1];
        const float dv2 = dinv[rb + 2];
        const float dv3 = dinv[rb + 3];
        #pragma unroll
        for (int c = 0; c < 4; ++c) {
            unsigned short* gp = G + (size_t)rb * FDIM + c * 16 + lr;
            gp[0 * FDIM] = f2bf(acc[c][0] * dv0);
            gp[1 * FDIM] = f2bf(acc[c][1] * dv1);
            gp[2 * FDIM] = f2bf(acc[c][2] * dv2);
            gp[3 * FDIM] = f2bf(acc[c][3] * dv3);
        }
    }
}

// ------- aggregate (r9 structure, 42 us): wave/node, half-wave pair-gather,
// 16-deep chained pipeline + binary tail. OUTBF16=1: ReLU + packed bf16 out.
#define GATHER2(ii, uu, off)  int ii = srcSorted[eb + 2*(off)]; \
                              unsigned int uu = Gu[(size_t)ii * 32 + fl];

template <int OUTBF16>
__global__ __launch_bounds__(256, 4) void aggregate(const unsigned int* __restrict__ Gu,
                                                    const int* __restrict__ rowStart,
                                                    const int* __restrict__ srcSorted,
                                                    const float* __restrict__ dinv,
                                                    const float* __restrict__ bias,
                                                    void* __restrict__ OUT, int N) {
    const int lane   = threadIdx.x & 63;
    const int half   = lane >> 5;        // 0: even edges, 1: odd edges
    const int fl     = lane & 31;        // uint index within row (features 2fl,2fl+1)
    const int waveId = blockIdx.x * (blockDim.x >> 6) + (threadIdx.x >> 6);
    const int nWaves = gridDim.x * (blockDim.x >> 6);
    const float2 bv  = reinterpret_cast<const float2*>(bias)[fl];

    for (int v = waveId; v < N; v += nWaves) {
        const int beg = rowStart[v];
        const int end = rowStart[v + 1];

        unsigned int su = 0;
        if (half == 0) su = Gu[(size_t)v * 32 + fl];
        float ax = lof(su), ay = hif(su);

        int e = beg;
        for (; e + 16 <= end; e += 16) {
            const int eb = e + half;
            GATHER2(i0, u0, 0) GATHER2(i1, u1, 1) GATHER2(i2, u2, 2) GATHER2(i3, u3, 3)
            GATHER2(i4, u4, 4) GATHER2(i5, u5, 5) GATHER2(i6, u6, 6) GATHER2(i7, u7, 7)
            ax += ((lof(u0) + lof(u1)) + (lof(u2) + lof(u3)))
                + ((lof(u4) + lof(u5)) + (lof(u6) + lof(u7)));
            ay += ((hif(u0) + hif(u1)) + (hif(u2) + hif(u3)))
                + ((hif(u4) + hif(u5)) + (hif(u6) + hif(u7)));
        }
        int rem = end - e;
        if (rem >= 8) {
            const int eb = e + half;
            GATHER2(i0, u0, 0) GATHER2(i1, u1, 1) GATHER2(i2, u2, 2) GATHER2(i3, u3, 3)
            ax += (lof(u0) + lof(u1)) + (lof(u2) + lof(u3));
            ay += (hif(u0) + hif(u1)) + (hif(u2) + hif(u3));
            e += 8; rem -= 8;
        }
        if (rem >= 4) {
            const int eb = e + half;
            GATHER2(i0, u0, 0) GATHER2(i1, u1, 1)
            ax += lof(u0) + lof(u1);
            ay += hif(u0) + hif(u1);
            e += 4; rem -= 4;
        }
        if (rem >= 2) {
            const int eb = e + half;
            GATHER2(i0, u0, 0)
            ax += lof(u0);
            ay += hif(u0);
            e += 2; rem -= 2;
        }
        if (rem) {
            int i0 = srcSorted[e];
            unsigned int u0 = 0;
            if (half == 0) u0 = Gu[(size_t)i0 * 32 + fl];
            ax += lof(u0);
            ay += hif(u0);
        }

        ax += __shfl_xor(ax, 32, 64);
        ay += __shfl_xor(ay, 32, 64);

        if (half == 0) {
            const float dv = dinv[v];
            float rx = ax * dv + bv.x;
            float ry = ay * dv + bv.y;
            if (OUTBF16) {                       // layer 1: ReLU + packed bf16
                rx = fmaxf(rx, 0.f); ry = fmaxf(ry, 0.f);
                unsigned int p = (unsigned)f2bf(rx) | ((unsigned)f2bf(ry) << 16);
                ((unsigned int*)OUT)[(size_t)v * 32 + fl] = p;
            } else {                             // layer 2: fp32 row-major out
                float2 r2; r2.x = rx; r2.y = ry;
                reinterpret_cast<float2*>((float*)OUT + (size_t)v * FDIM)[fl] = r2;
            }
        }
    }
}

extern "C" void kernel_launch(void* const* d_in, const int* in_sizes, int n_in,
                              void* d_out, int out_size, void* d_ws, size_t ws_size,
                              hipStream_t stream) {
    const float* x     = (const float*)d_in[0];
    const int*   edges = (const int*)d_in[1];   // int32 per harness contract
    const float* W1    = (const float*)d_in[2];
    const float* b1    = (const float*)d_in[3];
    const float* W2    = (const float*)d_in[4];
    const float* b2    = (const float*)d_in[5];
    float*       out   = (float*)d_out;

    const int N = in_sizes[0] / 128;   // 100000
    const int E = in_sizes[1] / 2;     // 1600000
    const int* srcIdx = edges;
    const int* dstIdx = edges + E;

    const int B1 = (N + NPB - 1) / NPB;         // 782 buckets
    const int B0 = 256;                          // phase-1 blocks
    const int chunk = (E + B0 - 1) / B0;         // 6250
    const int S  = B1 * B0;                      // scanned size (200192)
    const int nSB = (S + 2047) / 2048;           // 98 scan blocks (<=512)

    // workspace layout (256B aligned slices)
    char* ws = (char*)d_ws;
    size_t off = 0;
    auto alloc = [&](size_t bytes) { char* p = ws + off; off = (off + bytes + 255) & ~(size_t)255; return p; };
    float* dinv      = (float*)alloc((size_t)N * 4);
    int*   H         = (int*)  alloc((size_t)S * 4);
    int*   blockSums = (int*)  alloc(512 * 4);
    int*   rowStart  = (int*)  alloc((size_t)(N + 1) * 4);
    int*   srcSorted = (int*)  alloc((size_t)E * 4);
    unsigned short* g1  = (unsigned short*)alloc((size_t)N * FDIM * 2);  // bf16
    unsigned short* x2b = (unsigned short*)alloc((size_t)N * FDIM * 2);  // bf16 (h)
    int*   pairs     = (int*)x2b;       // alias: pairs (6.4MB) dead before x2b written
    unsigned short* g2 = g1;            // g1 dead after first aggregate

    bucket_hist   <<<B0, 256, 0, stream>>>(dstIdx, E, B1, chunk, B0, H);
    scanA         <<<nSB, 256, 0, stream>>>(H, S, blockSums);
    scanB         <<<1, 512, 0, stream>>>(blockSums, nSB);
    scanC         <<<nSB, 256, 0, stream>>>(H, S, blockSums);
    bucket_scatter<<<B0, 256, 0, stream>>>(srcIdx, dstIdx, E, B1, chunk, B0, H, pairs);
    bucket_csr    <<<B1, 256, 0, stream>>>(pairs, H, B0, E, N, dinv, rowStart, srcSorted);

    gemm_mfma<128, 0><<<768, 256, 0, stream>>>(x, W1, dinv, g1, N);
    aggregate<1>     <<<2048, 256, 0, stream>>>((const unsigned int*)g1, rowStart, srcSorted,
                                                dinv, b1, (void*)x2b, N);
    gemm_mfma<64, 1> <<<768, 256, 0, stream>>>((const float*)x2b, W2, dinv, g2, N);
    aggregate<0>     <<<2048, 256, 0, stream>>>((const unsigned int*)g2, rowStart, srcSorted,
                                                dinv, b2, (void*)out, N);
}